// Round 1
// baseline (101.391 us; speedup 1.0000x reference)
//
#include <hip/hip_runtime.h>

namespace {

constexpr int NQ = 10;
constexpr int NL = 3;

struct cplx { float re, im; };

__device__ __forceinline__ cplx cmul(cplx a, cplx b) {
  cplx r;
  r.re = fmaf(a.re, b.re, -a.im * b.im);
  r.im = fmaf(a.re, b.im,  a.im * b.re);
  return r;
}

// u*a + v*b (complex)
__device__ __forceinline__ cplx cmadd2(cplx u, cplx a, cplx v, cplx b) {
  cplx r;
  r.re = fmaf(u.re, a.re, fmaf(-u.im, a.im, fmaf(v.re, b.re, -v.im * b.im)));
  r.im = fmaf(u.re, a.im, fmaf( u.im, a.re, fmaf(v.re, b.im,  v.im * b.re)));
  return r;
}

__device__ __forceinline__ float fast_tanh(float x) {
  float xc = fminf(fmaxf(x, -10.f), 10.f);
  float e = __expf(2.f * xc);
  return __fdividef(e - 1.f, e + 1.f);
}

__global__ __launch_bounds__(256, 4)
void qgan_kernel(const float* __restrict__ z, const float* __restrict__ wts,
                 const float* __restrict__ W1, const float* __restrict__ b1,
                 const float* __restrict__ W2, const float* __restrict__ b2,
                 const float* __restrict__ W3, const float* __restrict__ b3,
                 float* __restrict__ out, int B)
{
  const int tid  = blockIdx.x * 256 + threadIdx.x;
  const int wv   = tid >> 6;        // one batch element per wave
  const int lane = threadIdx.x & 63;
  if (wv >= B) return;

  // ---- build Rot-gate U[l][q] (wave-uniform) ----
  auto buildU = [&](int l, int q, cplx& u00, cplx& u01, cplx& u10, cplx& u11) {
    const float* p = wts + (l * NQ + q) * 3;
    float a = p[0], bb = p[1], cc = p[2];
    float al = 0.5f * (a + cc), be = 0.5f * (a - cc), hb = 0.5f * bb;
    float ca = __cosf(al), sa = __sinf(al);
    float cbe = __cosf(be), sbe = __sinf(be);
    float cb = __cosf(hb), sb = __sinf(hb);
    u00 = {  cb * ca, -cb * sa };
    u01 = { -sb * cbe, -sb * sbe };
    u10 = {  sb * cbe, -sb * sbe };
    u11 = {  cb * ca,  cb * sa };
  };

  // ---- init: RY product state fused with layer-0 1q gates ----
  // amplitude index bits: bit b=9-w for wire w; lane holds bits 4..9, local bits 0..3
  cplx laneF = {1.f, 0.f};
  #pragma unroll
  for (int q = 0; q < 6; ++q) {           // wires 0..5 -> lane bits 5..0
    float zz = z[wv * NQ + q];
    zz = fminf(fmaxf(zz, -1.f), 1.f);
    float c0 = __cosf(0.5f * zz), s0 = __sinf(0.5f * zz);
    cplx u00, u01, u10, u11; buildU(0, q, u00, u01, u10, u11);
    cplx va = { fmaf(u00.re, c0, u01.re * s0), fmaf(u00.im, c0, u01.im * s0) };
    cplx vb = { fmaf(u10.re, c0, u11.re * s0), fmaf(u10.im, c0, u11.im * s0) };
    cplx f = ((lane >> (5 - q)) & 1) ? vb : va;
    laneF = (q == 0) ? f : cmul(laneF, f);
  }
  cplx va_[4], vb_[4];                     // wires 6..9 -> local bits 3..0
  #pragma unroll
  for (int q = 6; q < 10; ++q) {
    float zz = z[wv * NQ + q];
    zz = fminf(fmaxf(zz, -1.f), 1.f);
    float c0 = __cosf(0.5f * zz), s0 = __sinf(0.5f * zz);
    cplx u00, u01, u10, u11; buildU(0, q, u00, u01, u10, u11);
    va_[q - 6] = { fmaf(u00.re, c0, u01.re * s0), fmaf(u00.im, c0, u01.im * s0) };
    vb_[q - 6] = { fmaf(u10.re, c0, u11.re * s0), fmaf(u10.im, c0, u11.im * s0) };
  }

  cplx amp[16];
  {
    cplx P2[4];
    P2[0] = cmul(va_[2], va_[3]);   // wire8(bit1), wire9(bit0)
    P2[1] = cmul(va_[2], vb_[3]);
    P2[2] = cmul(vb_[2], va_[3]);
    P2[3] = cmul(vb_[2], vb_[3]);
    cplx g0 = cmul(laneF, va_[0]);  // wire6 = bit3
    cplx g1 = cmul(laneF, vb_[0]);
    #pragma unroll
    for (int t = 0; t < 16; ++t) {
      cplx t7 = ((t >> 2) & 1) ? vb_[1] : va_[1];   // wire7 = bit2
      cplx tt = cmul(t7, P2[t & 3]);
      amp[t] = cmul(((t >> 3) & 1) ? g1 : g0, tt);
    }
  }

  // ---- CNOT chain: (9,8)(8,7)(7,6)(6,5)(5,4) fused -> src = lane^(lane>>1);
  //      then (4,3) mixed; then (3,2)(2,1)(1,0) = static local perm t^(t>>1) ----
  auto chain = [&]() {
    int src = (lane ^ (lane >> 1)) & 63;
    #pragma unroll
    for (int t = 0; t < 16; ++t) {
      amp[t].re = __shfl(amp[t].re, src);
      amp[t].im = __shfl(amp[t].im, src);
    }
    bool ctrl = (lane & 1) != 0;           // state bit 4 controls local bit 3
    #pragma unroll
    for (int t = 0; t < 8; ++t) {
      cplx a = amp[t], b = amp[t | 8];
      amp[t]     = ctrl ? b : a;
      amp[t | 8] = ctrl ? a : b;
    }
    cplx tmp[16];
    #pragma unroll
    for (int t = 0; t < 16; ++t) tmp[t] = amp[t];
    #pragma unroll
    for (int t = 0; t < 16; ++t) amp[t] = tmp[t ^ (t >> 1)];
  };

  chain();  // after (fused) layer 0

  #pragma unroll
  for (int l = 1; l < NL; ++l) {
    #pragma unroll
    for (int q = 0; q < NQ; ++q) {
      cplx u00, u01, u10, u11; buildU(l, q, u00, u01, u10, u11);
      const int b = 9 - q;
      if (b >= 4) {                         // lane-bit gate
        const int kb = b - 4;
        bool hi = ((lane >> kb) & 1) != 0;
        cplx cA = hi ? u10 : u00;
        cplx cB = hi ? u11 : u01;
        #pragma unroll
        for (int t = 0; t < 16; ++t) {
          cplx o;
          o.re = __shfl_xor(amp[t].re, 1 << kb);
          o.im = __shfl_xor(amp[t].im, 1 << kb);
          cplx a0 = hi ? o : amp[t];
          cplx a1 = hi ? amp[t] : o;
          amp[t] = cmadd2(cA, a0, cB, a1);
        }
      } else {                              // local-bit gate
        const int lb = b;
        #pragma unroll
        for (int t0 = 0; t0 < 16; ++t0) {
          if (t0 & (1 << lb)) continue;
          int t1 = t0 | (1 << lb);
          cplx a0 = amp[t0], a1 = amp[t1];
          amp[t0] = cmadd2(u00, a0, u01, a1);
          amp[t1] = cmadd2(u10, a0, u11, a1);
        }
      }
    }
    if (l == 1) chain();
    // the layer-2 chain is folded into the parity-signed measurement below
  }

  // ---- measurement: Z on wire w after final chain == parity of bits (9-w)..9
  float p[16];
  #pragma unroll
  for (int t = 0; t < 16; ++t)
    p[t] = fmaf(amp[t].re, amp[t].re, amp[t].im * amp[t].im);

  float s_tot = 0.f, pw6 = 0.f, pw7 = 0.f, pw8 = 0.f, pw9 = 0.f;
  #pragma unroll
  for (int t = 0; t < 16; ++t) {
    s_tot += p[t];
    pw6 += (__popc(t & 0x8) & 1) ? -p[t] : p[t];
    pw7 += (__popc(t & 0xC) & 1) ? -p[t] : p[t];
    pw8 += (__popc(t & 0xE) & 1) ? -p[t] : p[t];
    pw9 += (__popc(t & 0xF) & 1) ? -p[t] : p[t];
  }

  float vals[10];
  const int   lm[10]  = {0x20, 0x30, 0x38, 0x3C, 0x3E, 0x3F, 0x3F, 0x3F, 0x3F, 0x3F};
  const float bs[10]  = {s_tot, s_tot, s_tot, s_tot, s_tot, s_tot, pw6, pw7, pw8, pw9};
  #pragma unroll
  for (int w2 = 0; w2 < 10; ++w2) {
    bool neg = (__popc(lane & lm[w2]) & 1) != 0;
    vals[w2] = neg ? -bs[w2] : bs[w2];
  }
  #pragma unroll
  for (int k = 0; k < 6; ++k) {
    #pragma unroll
    for (int w2 = 0; w2 < 10; ++w2)
      vals[w2] += __shfl_xor(vals[w2], 1 << k);
  }
  // all lanes now hold all 10 features

  // ---- MLP: 10 -> 32 (tanh) -> 16 (tanh) -> 1; sigmoid*0.2-0.1 == 0.1*tanh(raw/2)
  const int j = lane & 31;
  float acc = b1[j];
  #pragma unroll
  for (int i = 0; i < NQ; ++i) acc = fmaf(vals[i], W1[i * 32 + j], acc);
  float h1 = fast_tanh(acc);

  const int kk = lane & 15;
  float acc2 = b2[kk];
  #pragma unroll
  for (int jj = 0; jj < 32; ++jj) {
    float hv = __shfl(h1, jj);
    acc2 = fmaf(hv, W2[jj * 16 + kk], acc2);
  }
  float h2 = fast_tanh(acc2);

  float vv = (lane < 16) ? h2 * W3[lane] : 0.f;
  #pragma unroll
  for (int k = 0; k < 6; ++k) vv += __shfl_xor(vv, 1 << k);

  if (lane == 0) {
    float raw = vv + b3[0];
    out[wv] = 0.1f * fast_tanh(0.5f * raw);
  }
}

} // namespace

extern "C" void kernel_launch(void* const* d_in, const int* in_sizes, int n_in,
                              void* d_out, int out_size, void* d_ws, size_t ws_size,
                              hipStream_t stream) {
  const float* z   = (const float*)d_in[0];
  const float* wts = (const float*)d_in[1];
  const float* W1  = (const float*)d_in[2];
  const float* b1  = (const float*)d_in[3];
  const float* W2  = (const float*)d_in[4];
  const float* b2  = (const float*)d_in[5];
  const float* W3  = (const float*)d_in[6];
  const float* b3  = (const float*)d_in[7];
  float* out = (float*)d_out;

  int B = in_sizes[0] / NQ;                 // 4096
  int blocks = (B + 3) / 4;                 // 4 waves (batch elements) per 256-thr block
  hipLaunchKernelGGL(qgan_kernel, dim3(blocks), dim3(256), 0, stream,
                     z, wts, W1, b1, W2, b2, W3, b3, out, B);
}

// Round 2
// 93.288 us; speedup vs baseline: 1.0869x; 1.0869x over previous
//
#include <hip/hip_runtime.h>

namespace {

constexpr int NQ = 10;

struct cplx { float re, im; };

__device__ __forceinline__ cplx cmul(cplx a, cplx b) {
  cplx r;
  r.re = fmaf(a.re, b.re, -a.im * b.im);
  r.im = fmaf(a.re, b.im,  a.im * b.re);
  return r;
}

// u*a + v*b (complex)
__device__ __forceinline__ cplx cmadd2(cplx u, cplx a, cplx v, cplx b) {
  cplx r;
  r.re = fmaf(u.re, a.re, fmaf(-u.im, a.im, fmaf(v.re, b.re, -v.im * b.im)));
  r.im = fmaf(u.re, a.im, fmaf( u.im, a.re, fmaf(v.re, b.im,  v.im * b.re)));
  return r;
}

__device__ __forceinline__ cplx csel(bool c, cplx x, cplx y) {
  cplx r; r.re = c ? x.re : y.re; r.im = c ? x.im : y.im; return r;
}

__device__ __forceinline__ float fast_tanh(float x) {
  float xc = fminf(fmaxf(x, -10.f), 10.f);
  float e = __expf(2.f * xc);
  return __fdividef(e - 1.f, e + 1.f);
}

// ---- DPP cross-lane (VALU pipe, no DS) ----
// quad_perm xor1 = 0xB1, xor2 = 0x4E, xor3 = 0x1B; row_ror:8 (== xor8 in 16) = 0x128
template<int CTRL>
__device__ __forceinline__ float dppf(float v) {
  return __int_as_float(__builtin_amdgcn_update_dpp(0, __float_as_int(v), CTRL, 0xF, 0xF, true));
}
template<int CTRL>
__device__ __forceinline__ cplx dppc(cplx v) { return { dppf<CTRL>(v.re), dppf<CTRL>(v.im) }; }

__device__ __forceinline__ cplx shflxc(cplx v, int m) {
  cplx r; r.re = __shfl_xor(v.re, m); r.im = __shfl_xor(v.im, m); return r;
}

__device__ __forceinline__ float rdlane(float v, int l) {
  return __int_as_float(__builtin_amdgcn_readlane(__float_as_int(v), l));
}

// full-wave sum; result uniform across lanes. DS ops: 2 (xor4, xor16).
__device__ __forceinline__ float wave_sum(float v) {
  v += dppf<0xB1>(v);          // xor1
  v += dppf<0x4E>(v);          // xor2
  v += __shfl_xor(v, 4);       // xor4  (DS)
  v += dppf<0x128>(v);         // xor8
  v += __shfl_xor(v, 16);      // xor16 (DS)
  return rdlane(v, 0) + rdlane(v, 32);
}

__device__ __forceinline__ void loadU(const float* __restrict__ Ut, int g,
                                      cplx& u00, cplx& u01, cplx& u10, cplx& u11) {
  const float* p = Ut + g * 8;
  u00 = {p[0], p[1]}; u01 = {p[2], p[3]};
  u10 = {p[4], p[5]}; u11 = {p[6], p[7]};
}

// ---- gate templates (chain-folded layout) ----
// Pure lane-exchange gate via DS shuffle: pair = lane^LX, hi = parity(lane&HIL)
template<int LX, int HIL>
__device__ __forceinline__ void laneGateDS(cplx (&amp)[16], int lane,
    cplx u00, cplx u01, cplx u10, cplx u11) {
  bool hi = (__popc(lane & HIL) & 1) != 0;
  cplx cA = csel(hi, u11, u00), cB = csel(hi, u10, u01);
  #pragma unroll
  for (int t = 0; t < 16; ++t) {
    cplx o = shflxc(amp[t], LX);
    amp[t] = cmadd2(cA, amp[t], cB, o);
  }
}

// Pure lane-exchange gate via DPP (xor mask expressible as quad_perm)
template<int CTRL, int HIL>
__device__ __forceinline__ void laneGateDPP(cplx (&amp)[16], int lane,
    cplx u00, cplx u01, cplx u10, cplx u11) {
  bool hi = (__popc(lane & HIL) & 1) != 0;
  cplx cA = csel(hi, u11, u00), cB = csel(hi, u10, u01);
  #pragma unroll
  for (int t = 0; t < 16; ++t) {
    cplx o = dppc<CTRL>(amp[t]);
    amp[t] = cmadd2(cA, amp[t], cB, o);
  }
}

// Mixed gate: partner = (lane ^ dpp-xor, t ^ LOCX); hi = parity(lane&HIL) (pure lane)
template<int CTRL, int LOCX, int HIL>
__device__ __forceinline__ void mixedGate(cplx (&amp)[16], int lane,
    cplx u00, cplx u01, cplx u10, cplx u11) {
  bool hi = (__popc(lane & HIL) & 1) != 0;
  cplx cA = csel(hi, u11, u00), cB = csel(hi, u10, u01);
  #pragma unroll
  for (int t0 = 0; t0 < 16; ++t0) {
    if (t0 & LOCX) continue;
    const int t1 = t0 | LOCX;
    cplx o0 = dppc<CTRL>(amp[t1]);   // partner of t0
    cplx o1 = dppc<CTRL>(amp[t0]);   // partner of t1
    amp[t0] = cmadd2(cA, amp[t0], cB, o0);
    amp[t1] = cmadd2(cA, amp[t1], cB, o1);
  }
}

constexpr int hbit(int m) { return m >= 8 ? 8 : (m >= 4 ? 4 : (m >= 2 ? 2 : 1)); }

// Pure local gate: pair = t ^ PLOC; hi = parity(lane&HIL) ^ parity(t&HILOC)
template<int PLOC, int HIL, int HILOC>
__device__ __forceinline__ void localGate(cplx (&amp)[16], int lane,
    cplx u00, cplx u01, cplx u10, cplx u11) {
  bool h0 = (__popc(lane & HIL) & 1) != 0;       // hi when parity(t&HILOC)==0
  cplx cA0 = csel(h0, u11, u00), cB0 = csel(h0, u10, u01);
  cplx cA1 = csel(h0, u00, u11), cB1 = csel(h0, u01, u10);
  #pragma unroll
  for (int ta = 0; ta < 16; ++ta) {
    if (ta & hbit(PLOC)) continue;
    const int tb = ta ^ PLOC;
    const bool pa = (__popc(ta & HILOC) & 1) != 0;   // compile-time
    cplx aA = amp[ta], aB = amp[tb];
    if (!pa) {
      amp[ta] = cmadd2(cA0, aA, cB0, aB);
      amp[tb] = cmadd2(cA1, aB, cB1, aA);
    } else {
      amp[ta] = cmadd2(cA1, aA, cB1, aB);
      amp[tb] = cmadd2(cA0, aB, cB0, aA);
    }
  }
}

// ---- prep: 30 wave-uniform Rot matrices -> d_ws (960 B) ----
__global__ void qgan_prep(const float* __restrict__ wts, float* __restrict__ U) {
  int g = threadIdx.x;
  if (g >= 30) return;
  float a = wts[g * 3 + 0], b = wts[g * 3 + 1], c = wts[g * 3 + 2];
  float al = 0.5f * (a + c), be = 0.5f * (a - c), hb = 0.5f * b;
  float ca = cosf(al), sa = sinf(al);
  float cbe = cosf(be), sbe = sinf(be);
  float cb = cosf(hb), sb = sinf(hb);
  float* p = U + g * 8;
  p[0] =  cb * ca;  p[1] = -cb * sa;    // u00
  p[2] = -sb * cbe; p[3] = -sb * sbe;   // u01
  p[4] =  sb * cbe; p[5] = -sb * sbe;   // u10
  p[6] =  cb * ca;  p[7] =  cb * sa;    // u11
}

__global__ __launch_bounds__(256, 4)
void qgan_kernel(const float* __restrict__ z, const float* __restrict__ Ut,
                 const float* __restrict__ W1, const float* __restrict__ b1,
                 const float* __restrict__ W2, const float* __restrict__ b2,
                 const float* __restrict__ W3, const float* __restrict__ b3,
                 float* __restrict__ out, int B)
{
  const int tid  = blockIdx.x * 256 + threadIdx.x;
  const int lane = threadIdx.x & 63;
  const int wv   = __builtin_amdgcn_readfirstlane(tid >> 6);   // one elem per wave
  if (wv >= B) return;

  cplx u00, u01, u10, u11;

  // ---- init: RY product state fused with layer-0 1q gates (identity layout) ----
  cplx laneF = {1.f, 0.f};
  #pragma unroll
  for (int q = 0; q < 6; ++q) {              // wires 0..5 -> lane bits 5..0
    float zz = z[wv * NQ + q];
    zz = fminf(fmaxf(zz, -1.f), 1.f);
    float c0 = __cosf(0.5f * zz), s0 = __sinf(0.5f * zz);
    loadU(Ut, q, u00, u01, u10, u11);
    cplx va = { fmaf(u00.re, c0, u01.re * s0), fmaf(u00.im, c0, u01.im * s0) };
    cplx vb = { fmaf(u10.re, c0, u11.re * s0), fmaf(u10.im, c0, u11.im * s0) };
    cplx f = ((lane >> (5 - q)) & 1) ? vb : va;
    laneF = (q == 0) ? f : cmul(laneF, f);
  }
  cplx va_[4], vb_[4];                       // wires 6..9 -> local bits 3..0
  #pragma unroll
  for (int q = 6; q < 10; ++q) {
    float zz = z[wv * NQ + q];
    zz = fminf(fmaxf(zz, -1.f), 1.f);
    float c0 = __cosf(0.5f * zz), s0 = __sinf(0.5f * zz);
    loadU(Ut, q, u00, u01, u10, u11);
    va_[q - 6] = { fmaf(u00.re, c0, u01.re * s0), fmaf(u00.im, c0, u01.im * s0) };
    vb_[q - 6] = { fmaf(u10.re, c0, u11.re * s0), fmaf(u10.im, c0, u11.im * s0) };
  }

  cplx amp[16];
  {
    cplx P2[4];
    P2[0] = cmul(va_[2], va_[3]);
    P2[1] = cmul(va_[2], vb_[3]);
    P2[2] = cmul(vb_[2], va_[3]);
    P2[3] = cmul(vb_[2], vb_[3]);
    cplx g0 = cmul(laneF, va_[0]);           // wire6 = bit3
    cplx g1 = cmul(laneF, vb_[0]);
    #pragma unroll
    for (int t = 0; t < 16; ++t) {
      cplx t7 = ((t >> 2) & 1) ? vb_[1] : va_[1];
      cplx tt = cmul(t7, P2[t & 3]);
      amp[t] = cmul(((t >> 3) & 1) ? g1 : g0, tt);
    }
  }

  // ---- ALL THREE CNOT chains are folded (never physically permuted). ----
  // Layer 1 sees layout C^1: pair mask = e_b|e_{b-1}, hi mask = suffix(b).
  loadU(Ut, 10, u00,u01,u10,u11); laneGateDS <0x30, 0x20>(amp, lane, u00,u01,u10,u11);       // b=9
  loadU(Ut, 11, u00,u01,u10,u11); laneGateDS <0x18, 0x30>(amp, lane, u00,u01,u10,u11);       // b=8
  loadU(Ut, 12, u00,u01,u10,u11); laneGateDS <0x0C, 0x38>(amp, lane, u00,u01,u10,u11);       // b=7
  loadU(Ut, 13, u00,u01,u10,u11); laneGateDS <0x06, 0x3C>(amp, lane, u00,u01,u10,u11);       // b=6
  loadU(Ut, 14, u00,u01,u10,u11); laneGateDPP<0x1B, 0x3E>(amp, lane, u00,u01,u10,u11);       // b=5 xor3
  loadU(Ut, 15, u00,u01,u10,u11); mixedGate  <0xB1, 8, 0x3F>(amp, lane, u00,u01,u10,u11);    // b=4
  loadU(Ut, 16, u00,u01,u10,u11); localGate  <0xC, 0x3F, 0x8>(amp, lane, u00,u01,u10,u11);   // b=3
  loadU(Ut, 17, u00,u01,u10,u11); localGate  <0x6, 0x3F, 0xC>(amp, lane, u00,u01,u10,u11);   // b=2
  loadU(Ut, 18, u00,u01,u10,u11); localGate  <0x3, 0x3F, 0xE>(amp, lane, u00,u01,u10,u11);   // b=1
  loadU(Ut, 19, u00,u01,u10,u11); localGate  <0x1, 0x3F, 0xF>(amp, lane, u00,u01,u10,u11);   // b=0

  // Layer 2 sees layout C^2: pair mask = e_b^e_{b-2}, hi mask = {k>=b, k=b mod 2}.
  loadU(Ut, 20, u00,u01,u10,u11); laneGateDS <0x28, 0x20>(amp, lane, u00,u01,u10,u11);       // b=9
  loadU(Ut, 21, u00,u01,u10,u11); laneGateDS <0x14, 0x10>(amp, lane, u00,u01,u10,u11);       // b=8
  loadU(Ut, 22, u00,u01,u10,u11); laneGateDS <0x0A, 0x28>(amp, lane, u00,u01,u10,u11);       // b=7
  loadU(Ut, 23, u00,u01,u10,u11); laneGateDS <0x05, 0x14>(amp, lane, u00,u01,u10,u11);       // b=6
  loadU(Ut, 24, u00,u01,u10,u11); mixedGate  <0x4E, 8, 0x2A>(amp, lane, u00,u01,u10,u11);    // b=5 xor2
  loadU(Ut, 25, u00,u01,u10,u11); mixedGate  <0xB1, 4, 0x15>(amp, lane, u00,u01,u10,u11);    // b=4 xor1
  loadU(Ut, 26, u00,u01,u10,u11); localGate  <0xA, 0x2A, 0x8>(amp, lane, u00,u01,u10,u11);   // b=3
  loadU(Ut, 27, u00,u01,u10,u11); localGate  <0x5, 0x15, 0x4>(amp, lane, u00,u01,u10,u11);   // b=2
  loadU(Ut, 28, u00,u01,u10,u11); localGate  <0x2, 0x2A, 0xA>(amp, lane, u00,u01,u10,u11);   // b=1
  loadU(Ut, 29, u00,u01,u10,u11); localGate  <0x1, 0x15, 0x5>(amp, lane, u00,u01,u10,u11);   // b=0

  // ---- measurement under layout C^3: feature(wire w, b=9-w) mask = row b of C^3 ----
  float p[16];
  #pragma unroll
  for (int t = 0; t < 16; ++t)
    p[t] = fmaf(amp[t].re, amp[t].re, amp[t].im * amp[t].im);

  float s0 = 0.f, s8 = 0.f, sC = 0.f, s6 = 0.f, s3 = 0.f;
  #pragma unroll
  for (int t = 0; t < 16; ++t) {
    s0 += p[t];
    s8 += (__popc(t & 0x8) & 1) ? -p[t] : p[t];
    sC += (__popc(t & 0xC) & 1) ? -p[t] : p[t];
    s6 += (__popc(t & 0x6) & 1) ? -p[t] : p[t];
    s3 += (__popc(t & 0x3) & 1) ? -p[t] : p[t];
  }

  // lane masks = high 6 bits of row b of C^3; sources = local-signed sums
  const int   lmask[10] = {0x20,0x30,0x18,0x0C,0x26,0x33,0x19,0x0C,0x26,0x33};
  const float lsrc[10]  = {s0,  s0,  s0,  s0,  s0,  s0,  s8,  sC,  s6,  s3 };
  float feats[10];
  #pragma unroll
  for (int w = 0; w < 10; ++w) {
    int par = __popc(lane & lmask[w]) & 1;
    float v = __int_as_float(__float_as_int(lsrc[w]) ^ (par << 31));
    feats[w] = wave_sum(v);
  }

  // ---- MLP: 10 -> 32 (tanh) -> 16 (tanh) -> 1; sigmoid*0.2-0.1 == 0.1*tanh(raw/2)
  const int j = lane & 31;
  float acc = b1[j];
  #pragma unroll
  for (int i = 0; i < NQ; ++i) acc = fmaf(feats[i], W1[i * 32 + j], acc);
  float h1 = fast_tanh(acc);

  const int k = lane & 15;
  float acc2 = b2[k];
  #pragma unroll
  for (int jj = 0; jj < 32; ++jj)
    acc2 = fmaf(rdlane(h1, jj), W2[jj * 16 + k], acc2);   // readlane: 0 DS
  float h2 = fast_tanh(acc2);

  float vv = h2 * W3[k];
  vv += dppf<0xB1>(vv);        // xor1
  vv += dppf<0x4E>(vv);        // xor2
  vv += __shfl_xor(vv, 4);     // xor4 (DS)
  vv += dppf<0x128>(vv);       // xor8

  if (lane == 0) out[wv] = 0.1f * fast_tanh(0.5f * (vv + b3[0]));
}

} // namespace

extern "C" void kernel_launch(void* const* d_in, const int* in_sizes, int n_in,
                              void* d_out, int out_size, void* d_ws, size_t ws_size,
                              hipStream_t stream) {
  const float* z   = (const float*)d_in[0];
  const float* wts = (const float*)d_in[1];
  const float* W1  = (const float*)d_in[2];
  const float* b1  = (const float*)d_in[3];
  const float* W2  = (const float*)d_in[4];
  const float* b2  = (const float*)d_in[5];
  const float* W3  = (const float*)d_in[6];
  const float* b3  = (const float*)d_in[7];
  float* out = (float*)d_out;
  float* U   = (float*)d_ws;                // 30*8 floats = 960 B

  int B = in_sizes[0] / NQ;                 // 4096
  hipLaunchKernelGGL(qgan_prep, dim3(1), dim3(32), 0, stream, wts, U);
  int blocks = (B + 3) / 4;                 // 4 waves (elements) per 256-thread block
  hipLaunchKernelGGL(qgan_kernel, dim3(blocks), dim3(256), 0, stream,
                     z, U, W1, b1, W2, b2, W3, b3, out, B);
}

// Round 3
// 88.358 us; speedup vs baseline: 1.1475x; 1.0558x over previous
//
#include <hip/hip_runtime.h>

namespace {

constexpr int NQ = 10;

typedef float v2f __attribute__((ext_vector_type(2)));

// ---- lane / DPP / DS primitives ----
__device__ __forceinline__ float rdlane(float v, int l) {
  return __int_as_float(__builtin_amdgcn_readlane(__float_as_int(v), l));
}
// DPP ctrl: quad_perm xor1=0xB1 xor2=0x4E xor3=0x1B; row_ror:8=0x128 (xor8);
// row_mirror=0x140 (xor15); row_half_mirror=0x141 (xor7)
template<int CTRL>
__device__ __forceinline__ float dppf(float v) {
  return __int_as_float(__builtin_amdgcn_update_dpp(0, __float_as_int(v), CTRL, 0xF, 0xF, true));
}
template<int CTRL>
__device__ __forceinline__ v2f dppv(v2f v) { return v2f{dppf<CTRL>(v.x), dppf<CTRL>(v.y)}; }
template<int C1, int C2>
__device__ __forceinline__ v2f dppv2(v2f v) { return dppv<C2>(dppv<C1>(v)); }

template<int PAT>   // ds_swizzle BitMode: (xor<<10)|(or<<5)|and
__device__ __forceinline__ v2f swzv(v2f v) {
  return v2f{ __int_as_float(__builtin_amdgcn_ds_swizzle(__float_as_int(v.x), PAT)),
              __int_as_float(__builtin_amdgcn_ds_swizzle(__float_as_int(v.y), PAT)) };
}
__device__ __forceinline__ v2f shflx(v2f v, int m) {
  return v2f{ __shfl_xor(v.x, m), __shfl_xor(v.y, m) };
}

// ---- packed complex math (targets v_pk_fma_f32) ----
__device__ __forceinline__ v2f pfma(v2f a, v2f b, v2f c) { return __builtin_elementwise_fma(a, b, c); }
__device__ __forceinline__ v2f swp(v2f a) { return v2f{a.y, a.x}; }
__device__ __forceinline__ v2f cmulv(v2f a, v2f b) {           // complex a*b
  return pfma(swp(b), v2f{-a.y, a.y}, b * v2f{a.x, a.x});
}
__device__ __forceinline__ v2f vsel(bool c, v2f a, v2f b) {
  return v2f{ c ? a.x : b.x, c ? a.y : b.y };
}
struct pkco { v2f rA, iA, rB, iB; };                            // packed 2x2 coeffs
__device__ __forceinline__ pkco mkco(v2f cA, v2f cB) {
  return pkco{ v2f{cA.x, cA.x}, v2f{-cA.y, cA.y}, v2f{cB.x, cB.x}, v2f{-cB.y, cB.y} };
}
// cA*a + cB*o (complex), 4 packed ops
__device__ __forceinline__ v2f capply(const pkco& c, v2f a, v2f o) {
  v2f r = a * c.rA;
  r = pfma(swp(a), c.iA, r);
  r = pfma(o, c.rB, r);
  r = pfma(swp(o), c.iB, r);
  return r;
}

// full-wave sum, uniform result; 1 DS op (xor16)
__device__ __forceinline__ float wave_sum(float v) {
  v += dppf<0xB1>(v);                      // xor1
  v += dppf<0x4E>(v);                      // xor2
  v += dppf<0x1B>(dppf<0x141>(v));         // xor4 = xor7 o xor3
  v += dppf<0x128>(v);                     // xor8
  v += __shfl_xor(v, 16);                  // xor16 (DS)
  return rdlane(v, 0) + rdlane(v, 32);
}

// ---- per-lane Rot matrices, broadcast by readlane ----
struct Umat { float r00,i00,r01,i01,r10,i10,r11,i11; };
__device__ __forceinline__ void getU(const Umat& m, int g,
                                     v2f& u00, v2f& u01, v2f& u10, v2f& u11) {
  u00 = v2f{rdlane(m.r00, g), rdlane(m.i00, g)};
  u01 = v2f{rdlane(m.r01, g), rdlane(m.i01, g)};
  u10 = v2f{rdlane(m.r10, g), rdlane(m.i10, g)};
  u11 = v2f{rdlane(m.r11, g), rdlane(m.i11, g)};
}

template<int HIL>
__device__ __forceinline__ pkco gateco(int lane, v2f u00, v2f u01, v2f u10, v2f u11) {
  bool hi = (__popc(lane & HIL) & 1) != 0;
  return mkco(vsel(hi, u11, u00), vsel(hi, u10, u01));
}

// ---- gate templates (all three CNOT chains algebraically folded) ----
template<int LX, int HIL>
__device__ __forceinline__ void gate_shfl(v2f (&amp)[16], int lane, v2f u00,v2f u01,v2f u10,v2f u11) {
  pkco c = gateco<HIL>(lane, u00,u01,u10,u11);
  #pragma unroll
  for (int t = 0; t < 16; ++t) amp[t] = capply(c, amp[t], shflx(amp[t], LX));
}
template<int PAT, int HIL>
__device__ __forceinline__ void gate_swz(v2f (&amp)[16], int lane, v2f u00,v2f u01,v2f u10,v2f u11) {
  pkco c = gateco<HIL>(lane, u00,u01,u10,u11);
  #pragma unroll
  for (int t = 0; t < 16; ++t) amp[t] = capply(c, amp[t], swzv<PAT>(amp[t]));
}
template<int C1, int HIL>
__device__ __forceinline__ void gate_dpp1(v2f (&amp)[16], int lane, v2f u00,v2f u01,v2f u10,v2f u11) {
  pkco c = gateco<HIL>(lane, u00,u01,u10,u11);
  #pragma unroll
  for (int t = 0; t < 16; ++t) amp[t] = capply(c, amp[t], dppv<C1>(amp[t]));
}
template<int C1, int C2, int HIL>
__device__ __forceinline__ void gate_dpp2(v2f (&amp)[16], int lane, v2f u00,v2f u01,v2f u10,v2f u11) {
  pkco c = gateco<HIL>(lane, u00,u01,u10,u11);
  #pragma unroll
  for (int t = 0; t < 16; ++t) amp[t] = capply(c, amp[t], dppv2<C1,C2>(amp[t]));
}
template<int CTRL, int LOCX, int HIL>
__device__ __forceinline__ void gate_mixed(v2f (&amp)[16], int lane, v2f u00,v2f u01,v2f u10,v2f u11) {
  pkco c = gateco<HIL>(lane, u00,u01,u10,u11);
  #pragma unroll
  for (int t0 = 0; t0 < 16; ++t0) {
    if (t0 & LOCX) continue;
    const int t1 = t0 | LOCX;
    v2f o0 = dppv<CTRL>(amp[t1]);
    v2f o1 = dppv<CTRL>(amp[t0]);
    amp[t0] = capply(c, amp[t0], o0);
    amp[t1] = capply(c, amp[t1], o1);
  }
}
constexpr int hbit(int m) { return m >= 8 ? 8 : (m >= 4 ? 4 : (m >= 2 ? 2 : 1)); }
template<int PLOC, int HIL, int HILOC>
__device__ __forceinline__ void gate_local(v2f (&amp)[16], int lane, v2f u00,v2f u01,v2f u10,v2f u11) {
  bool h0 = (__popc(lane & HIL) & 1) != 0;
  pkco c0 = mkco(vsel(h0, u11, u00), vsel(h0, u10, u01));
  pkco c1 = mkco(vsel(h0, u00, u11), vsel(h0, u01, u10));
  #pragma unroll
  for (int ta = 0; ta < 16; ++ta) {
    if (ta & hbit(PLOC)) continue;
    const int tb = ta ^ PLOC;
    const bool pa = (__popc(ta & HILOC) & 1) != 0;   // compile-time
    v2f aA = amp[ta], aB = amp[tb];
    if (!pa) { amp[ta] = capply(c0, aA, aB); amp[tb] = capply(c1, aB, aA); }
    else     { amp[ta] = capply(c1, aA, aB); amp[tb] = capply(c0, aB, aA); }
  }
}

__device__ __forceinline__ float fast_tanh(float x) {
  float xc = fminf(fmaxf(x, -10.f), 10.f);
  float e = __expf(2.f * xc);
  return __fdividef(e - 1.f, e + 1.f);
}

__global__ __launch_bounds__(256, 4)
void qgan_kernel(const float* __restrict__ z, const float* __restrict__ wts,
                 const float* __restrict__ W1, const float* __restrict__ b1,
                 const float* __restrict__ W2, const float* __restrict__ b2,
                 const float* __restrict__ W3, const float* __restrict__ b3,
                 float* __restrict__ out, int B)
{
  const int tid  = blockIdx.x * 256 + threadIdx.x;
  const int lane = threadIdx.x & 63;
  const int wv   = __builtin_amdgcn_readfirstlane(tid >> 6);   // one elem per wave
  if (wv >= B) return;

  // ---- 30 Rot matrices computed lane-parallel (lane g -> gate g), no prep kernel ----
  Umat m;
  {
    int g = (lane < 30) ? lane : 0;
    float wa = wts[g * 3 + 0], wb = wts[g * 3 + 1], wc = wts[g * 3 + 2];
    float al = 0.5f * (wa + wc), be = 0.5f * (wa - wc), hb = 0.5f * wb;
    float ca = __cosf(al),  sa = __sinf(al);
    float cbe = __cosf(be), sbe = __sinf(be);
    float cb = __cosf(hb),  sb = __sinf(hb);
    m.r00 =  cb * ca;  m.i00 = -cb * sa;
    m.r01 = -sb * cbe; m.i01 = -sb * sbe;
    m.r10 =  sb * cbe; m.i10 = -sb * sbe;
    m.r11 =  cb * ca;  m.i11 =  cb * sa;
  }

  v2f u00, u01, u10, u11;
  const float* zp = z + wv * NQ;           // wave-uniform -> scalar loads

  // ---- init: RY product state fused with layer-0 1q gates (identity layout) ----
  v2f laneF = {1.f, 0.f};
  #pragma unroll
  for (int q = 0; q < 6; ++q) {            // wires 0..5 -> lane bits 5..0
    float zz = fminf(fmaxf(zp[q], -1.f), 1.f);
    float c0 = __cosf(0.5f * zz), s0 = __sinf(0.5f * zz);
    getU(m, q, u00, u01, u10, u11);
    v2f va = pfma(u01, v2f{s0, s0}, u00 * v2f{c0, c0});
    v2f vb = pfma(u11, v2f{s0, s0}, u10 * v2f{c0, c0});
    v2f f = vsel((lane >> (5 - q)) & 1, vb, va);
    laneF = (q == 0) ? f : cmulv(laneF, f);
  }
  v2f va_[4], vb_[4];                      // wires 6..9 -> local bits 3..0
  #pragma unroll
  for (int q = 6; q < 10; ++q) {
    float zz = fminf(fmaxf(zp[q], -1.f), 1.f);
    float c0 = __cosf(0.5f * zz), s0 = __sinf(0.5f * zz);
    getU(m, q, u00, u01, u10, u11);
    va_[q - 6] = pfma(u01, v2f{s0, s0}, u00 * v2f{c0, c0});
    vb_[q - 6] = pfma(u11, v2f{s0, s0}, u10 * v2f{c0, c0});
  }

  v2f amp[16];
  {
    v2f P2[4];
    P2[0] = cmulv(va_[2], va_[3]);
    P2[1] = cmulv(va_[2], vb_[3]);
    P2[2] = cmulv(vb_[2], va_[3]);
    P2[3] = cmulv(vb_[2], vb_[3]);
    v2f g0 = cmulv(laneF, va_[0]);         // wire6 = bit3
    v2f g1 = cmulv(laneF, vb_[0]);
    #pragma unroll
    for (int t = 0; t < 16; ++t) {
      v2f t7 = ((t >> 2) & 1) ? vb_[1] : va_[1];
      v2f tt = cmulv(t7, P2[t & 3]);
      amp[t] = cmulv(((t >> 3) & 1) ? g1 : g0, tt);
    }
  }

  // ---- Layer 1 under layout C^1 ----
  getU(m, 10, u00,u01,u10,u11); gate_shfl <0x30, 0x20>(amp, lane, u00,u01,u10,u11);        // b=9
  getU(m, 11, u00,u01,u10,u11); gate_swz  <0x601F, 0x30>(amp, lane, u00,u01,u10,u11);      // b=8 xor 0x18
  getU(m, 12, u00,u01,u10,u11); gate_dpp2 <0x140, 0x1B, 0x38>(amp, lane, u00,u01,u10,u11); // b=7 xorC=15^3
  getU(m, 13, u00,u01,u10,u11); gate_dpp2 <0x141, 0xB1, 0x3C>(amp, lane, u00,u01,u10,u11); // b=6 xor6=7^1
  getU(m, 14, u00,u01,u10,u11); gate_dpp1 <0x1B, 0x3E>(amp, lane, u00,u01,u10,u11);        // b=5 xor3
  getU(m, 15, u00,u01,u10,u11); gate_mixed<0xB1, 8, 0x3F>(amp, lane, u00,u01,u10,u11);     // b=4
  getU(m, 16, u00,u01,u10,u11); gate_local<0xC, 0x3F, 0x8>(amp, lane, u00,u01,u10,u11);    // b=3
  getU(m, 17, u00,u01,u10,u11); gate_local<0x6, 0x3F, 0xC>(amp, lane, u00,u01,u10,u11);    // b=2
  getU(m, 18, u00,u01,u10,u11); gate_local<0x3, 0x3F, 0xE>(amp, lane, u00,u01,u10,u11);    // b=1
  getU(m, 19, u00,u01,u10,u11); gate_local<0x1, 0x3F, 0xF>(amp, lane, u00,u01,u10,u11);    // b=0

  // ---- Layer 2 under layout C^2 ----
  getU(m, 20, u00,u01,u10,u11); gate_shfl <0x28, 0x20>(amp, lane, u00,u01,u10,u11);        // b=9
  getU(m, 21, u00,u01,u10,u11); gate_swz  <0x501F, 0x10>(amp, lane, u00,u01,u10,u11);      // b=8 xor 0x14
  getU(m, 22, u00,u01,u10,u11); gate_dpp2 <0x128, 0x4E, 0x28>(amp, lane, u00,u01,u10,u11); // b=7 xorA=8^2
  getU(m, 23, u00,u01,u10,u11); gate_dpp2 <0x141, 0x4E, 0x14>(amp, lane, u00,u01,u10,u11); // b=6 xor5=7^2
  getU(m, 24, u00,u01,u10,u11); gate_mixed<0x4E, 8, 0x2A>(amp, lane, u00,u01,u10,u11);     // b=5
  getU(m, 25, u00,u01,u10,u11); gate_mixed<0xB1, 4, 0x15>(amp, lane, u00,u01,u10,u11);     // b=4
  getU(m, 26, u00,u01,u10,u11); gate_local<0xA, 0x2A, 0x8>(amp, lane, u00,u01,u10,u11);    // b=3
  getU(m, 27, u00,u01,u10,u11); gate_local<0x5, 0x15, 0x4>(amp, lane, u00,u01,u10,u11);    // b=2
  getU(m, 28, u00,u01,u10,u11); gate_local<0x2, 0x2A, 0xA>(amp, lane, u00,u01,u10,u11);    // b=1
  getU(m, 29, u00,u01,u10,u11); gate_local<0x1, 0x15, 0x5>(amp, lane, u00,u01,u10,u11);    // b=0

  // ---- measurement under layout C^3 (final chain folded into parity masks) ----
  float p[16];
  #pragma unroll
  for (int t = 0; t < 16; ++t) {
    v2f q2 = amp[t] * amp[t];
    p[t] = q2.x + q2.y;
  }
  float s0 = 0.f, s8 = 0.f, sC = 0.f, s6 = 0.f, s3 = 0.f;
  #pragma unroll
  for (int t = 0; t < 16; ++t) {
    s0 += p[t];
    s8 += (__popc(t & 0x8) & 1) ? -p[t] : p[t];
    sC += (__popc(t & 0xC) & 1) ? -p[t] : p[t];
    s6 += (__popc(t & 0x6) & 1) ? -p[t] : p[t];
    s3 += (__popc(t & 0x3) & 1) ? -p[t] : p[t];
  }
  const int   lmask[10] = {0x20,0x30,0x18,0x0C,0x26,0x33,0x19,0x0C,0x26,0x33};
  const float lsrc[10]  = {s0,  s0,  s0,  s0,  s0,  s0,  s8,  sC,  s6,  s3 };
  float feats[10];
  #pragma unroll
  for (int w = 0; w < 10; ++w) {
    int par = __popc(lane & lmask[w]) & 1;
    float v = __int_as_float(__float_as_int(lsrc[w]) ^ (par << 31));
    feats[w] = wave_sum(v);
  }

  // ---- MLP: 10->32 tanh ->16 tanh ->1 ; sigmoid*0.2-0.1 == 0.1*tanh(raw/2) ----
  const int j = lane & 31;
  float acc = b1[j];
  #pragma unroll
  for (int i = 0; i < NQ; ++i) acc = fmaf(feats[i], W1[i * 32 + j], acc);
  float h1 = fast_tanh(acc);

  const int k = lane & 15;
  float acc2 = b2[k];
  #pragma unroll
  for (int jj = 0; jj < 32; ++jj)
    acc2 = fmaf(rdlane(h1, jj), W2[jj * 16 + k], acc2);     // readlane: 0 DS
  float h2 = fast_tanh(acc2);

  float vv = h2 * W3[k];
  vv += dppf<0xB1>(vv);
  vv += dppf<0x4E>(vv);
  vv += dppf<0x1B>(dppf<0x141>(vv));   // xor4 via DPP chain
  vv += dppf<0x128>(vv);

  if (lane == 0) out[wv] = 0.1f * fast_tanh(0.5f * (vv + b3[0]));
}

} // namespace

extern "C" void kernel_launch(void* const* d_in, const int* in_sizes, int n_in,
                              void* d_out, int out_size, void* d_ws, size_t ws_size,
                              hipStream_t stream) {
  const float* z   = (const float*)d_in[0];
  const float* wts = (const float*)d_in[1];
  const float* W1  = (const float*)d_in[2];
  const float* b1  = (const float*)d_in[3];
  const float* W2  = (const float*)d_in[4];
  const float* b2  = (const float*)d_in[5];
  const float* W3  = (const float*)d_in[6];
  const float* b3  = (const float*)d_in[7];
  float* out = (float*)d_out;
  (void)d_ws; (void)ws_size;

  int B = in_sizes[0] / NQ;                 // 4096
  int blocks = (B + 3) / 4;                 // 4 waves (elements) per 256-thread block
  hipLaunchKernelGGL(qgan_kernel, dim3(blocks), dim3(256), 0, stream,
                     z, wts, W1, b1, W2, b2, W3, b3, out, B);
}